// Round 2
// baseline (1225.518 us; speedup 1.0000x reference)
//
#include <hip/hip_runtime.h>

#pragma clang fp contract(off)

#define HH 256
#define WW 256
#define NVERTS 6890
#define NFACES 13776
#define BIGF 1000000000.0f
#define EPSF 1e-8f
#define CHUNKF 128

// c(i) = ((i+0.5)/256)*2 - 1  -- exact in f32, matches reference pixel coords
__device__ __forceinline__ float pixc(int i) {
    return __fsub_rn(__fmul_rn(__fdiv_rn(__fadd_rn((float)i, 0.5f), 256.0f), 2.0f), 1.0f);
}

// ---------------------------------------------------------------------------
// Kernel 1: per (b, face) precompute.
// rast[idx*3+0] = {x2, y2, A, B}
// rast[idx*3+1] = {C, D, inv, 0}
// rast[idx*3+2] = {z0, z1, z2, face_id_bits}
// Degenerate (|denom|<EPS): A=B=C=D=0, inv=1 -> w0=w1=0, w2=1, depth=BIG exact
// -> never wins, identical to reference's inside &= |denom|>=EPS.
// flowg[idx*2+0] = {g0x,g0y,g1x,g1y}, flowg[idx*2+1] = {g2x,g2y,0,0}
// ---------------------------------------------------------------------------
__global__ __launch_bounds__(256) void precompute_kernel(
    const float* __restrict__ src_cam, const float* __restrict__ src_verts,
    const float* __restrict__ tgt_cam, const float* __restrict__ tgt_verts,
    const int* __restrict__ faces,
    float4* __restrict__ rast, float4* __restrict__ flowg, int B)
{
    int idx = blockIdx.x * blockDim.x + threadIdx.x;
    if (idx >= B * NFACES) return;
    int b = idx / NFACES;
    int f = idx - b * NFACES;
    int i0 = faces[3*f+0], i1 = faces[3*f+1], i2 = faces[3*f+2];

    float tc0 = tgt_cam[3*b+0], tc1 = tgt_cam[3*b+1], tc2 = tgt_cam[3*b+2];
    const float* tv = tgt_verts + (size_t)b * NVERTS * 3;
    float x0 = __fmul_rn(tc0, __fadd_rn(tv[3*i0+0], tc1));
    float y0 = -__fmul_rn(tc0, __fadd_rn(tv[3*i0+1], tc2));
    float z0 = tv[3*i0+2];
    float x1 = __fmul_rn(tc0, __fadd_rn(tv[3*i1+0], tc1));
    float y1 = -__fmul_rn(tc0, __fadd_rn(tv[3*i1+1], tc2));
    float z1 = tv[3*i1+2];
    float x2 = __fmul_rn(tc0, __fadd_rn(tv[3*i2+0], tc1));
    float y2 = -__fmul_rn(tc0, __fadd_rn(tv[3*i2+1], tc2));
    float z2 = tv[3*i2+2];

    float A  = __fsub_rn(y1, y2);
    float D  = __fsub_rn(x0, x2);
    float Bc = __fsub_rn(x2, x1);
    float E  = __fsub_rn(y0, y2);
    float denom = __fadd_rn(__fmul_rn(A, D), __fmul_rn(Bc, E));
    bool valid = (fabsf(denom) >= EPSF);
    float inv = __fdiv_rn(1.0f, valid ? denom : 1.0f);
    float Cc = __fsub_rn(y2, y0);

    float4 r0, r1, r2;
    if (valid) {
        r0 = make_float4(x2, y2, A, Bc);
        r1 = make_float4(Cc, D, inv, 0.0f);
        r2 = make_float4(z0, z1, z2, __int_as_float(f));
    } else {
        r0 = make_float4(0.0f, 0.0f, 0.0f, 0.0f);
        r1 = make_float4(0.0f, 0.0f, 1.0f, 0.0f);
        r2 = make_float4(BIGF, BIGF, BIGF, __int_as_float(f));
    }
    rast[(size_t)idx*3+0] = r0;
    rast[(size_t)idx*3+1] = r1;
    rast[(size_t)idx*3+2] = r2;

    float sc0 = src_cam[3*b+0], sc1 = src_cam[3*b+1], sc2 = src_cam[3*b+2];
    const float* sv = src_verts + (size_t)b * NVERTS * 3;
    float g0x = __fmul_rn(sc0, __fadd_rn(sv[3*i0+0], sc1));
    float g0y = __fmul_rn(sc0, __fadd_rn(sv[3*i0+1], sc2));
    float g1x = __fmul_rn(sc0, __fadd_rn(sv[3*i1+0], sc1));
    float g1y = __fmul_rn(sc0, __fadd_rn(sv[3*i1+1], sc2));
    float g2x = __fmul_rn(sc0, __fadd_rn(sv[3*i2+0], sc1));
    float g2y = __fmul_rn(sc0, __fadd_rn(sv[3*i2+1], sc2));
    flowg[(size_t)idx*2+0] = make_float4(g0x, g0y, g1x, g1y);
    flowg[(size_t)idx*2+1] = make_float4(g2x, g2y, 0.0f, 0.0f);
}

// ---------------------------------------------------------------------------
// Kernel 2: per-tile face lists. Interval-arithmetic cull: keep face unless
// one of the computed barycentric constraints is provably < 0 over the whole
// tile, including f32 rounding margins (1e-6 relative, ~8x eps headroom).
// Conservative even for sliver faces (tiny |denom|) whose computed-inside
// set extends far beyond the vertex bbox. Ordered compaction keeps ascending
// face order (needed for the strict-< tie-break to match the reference scan).
// ---------------------------------------------------------------------------
__global__ __launch_bounds__(256) void bin_kernel(
    const float4* __restrict__ rast, int* __restrict__ lists,
    int* __restrict__ counts, int B)
{
    int tile = blockIdx.x;          // 0..255
    int b = blockIdx.y;
    int tX = tile & 15, tY = tile >> 4;
    float txmin = pixc(tX * 16), txmax = pixc(tX * 16 + 15);
    float tymin = pixc(tY * 16), tymax = pixc(tY * 16 + 15);

    __shared__ int wcnt[4];
    int lane = threadIdx.x & 63;
    int wv = threadIdx.x >> 6;
    const float4* rb = rast + (size_t)b * NFACES * 3;
    int* mylist = lists + ((size_t)b * 256 + tile) * NFACES;
    int total = 0;

    for (int base = 0; base < NFACES; base += 256) {
        int f = base + threadIdx.x;
        bool pass = false;
        if (f < NFACES) {
            float4 r0 = rb[(size_t)f*3+0];
            float4 r1 = rb[(size_t)f*3+1];
            float dx0 = txmin - r0.x, dx1 = txmax - r0.x;
            float dy0 = tymin - r0.y, dy1 = tymax - r0.y;
            float mx = fmaxf(fabsf(dx0), fabsf(dx1));
            float my = fmaxf(fabsf(dy0), fabsf(dy1));
            float inv = r1.z, ainv = fabsf(inv);
            // t0 = A*dx + B*dy
            float t0max = fmaxf(r0.z*dx0, r0.z*dx1) + fmaxf(r0.w*dy0, r0.w*dy1);
            float t0min = fminf(r0.z*dx0, r0.z*dx1) + fminf(r0.w*dy0, r0.w*dy1);
            float w0max = fmaxf(t0max*inv, t0min*inv);
            float w0min = fminf(t0max*inv, t0min*inv);
            float am0 = fabsf(r0.z)*mx + fabsf(r0.w)*my;
            float M0 = 1e-6f * (am0*ainv + 1.0f + fmaxf(fabsf(w0max), fabsf(w0min)));
            // t1 = C*dx + D*dy
            float t1max = fmaxf(r1.x*dx0, r1.x*dx1) + fmaxf(r1.y*dy0, r1.y*dy1);
            float t1min = fminf(r1.x*dx0, r1.x*dx1) + fminf(r1.y*dy0, r1.y*dy1);
            float w1max = fmaxf(t1max*inv, t1min*inv);
            float w1min = fminf(t1max*inv, t1min*inv);
            float am1 = fabsf(r1.x)*mx + fabsf(r1.y)*my;
            float M1 = 1e-6f * (am1*ainv + 1.0f + fmaxf(fabsf(w1max), fabsf(w1min)));
            float M2 = M0 + M1 + 1e-6f * (1.0f + fabsf(w0min) + fabsf(w1min));
            float w2max = 1.0f - w0min - w1min + M2;
            pass = (w0max + M0 >= 0.0f) && (w1max + M1 >= 0.0f) && (w2max >= 0.0f);
        }
        unsigned long long m = __ballot(pass);
        if (lane == 0) wcnt[wv] = __popcll(m);
        __syncthreads();
        int off = total;
        for (int w = 0; w < wv; ++w) off += wcnt[w];
        if (pass) {
            int pre = __popcll(m & ((1ull << lane) - 1ull));
            mylist[off + pre] = f;
        }
        total += wcnt[0] + wcnt[1] + wcnt[2] + wcnt[3];
        __syncthreads();
    }
    if (threadIdx.x == 0) counts[b * 256 + tile] = total;
}

// ---------------------------------------------------------------------------
// Kernel 3: raster (z-buffer scan over tile's face list) + flow + grid sample.
// 64 threads = 8x8 pixel quadrant of a 16x16 tile. Faces staged into LDS in
// 128-face chunks; inner loop reads are wave-uniform (broadcast, no bank
// conflicts). All depth-path arithmetic uses _rn intrinsics to match the
// f32 reference bitwise (no FMA contraction).
// ---------------------------------------------------------------------------
__global__ __launch_bounds__(64) void raster_kernel(
    const float4* __restrict__ rast, const float4* __restrict__ flowg,
    const int* __restrict__ lists, const int* __restrict__ counts,
    const float* __restrict__ src_img, float* __restrict__ out, int B)
{
    __shared__ float4 sData[CHUNKF * 3];
    int tX = blockIdx.x, tY = blockIdx.y;
    int quad = blockIdx.z & 3;
    int b = blockIdx.z >> 2;
    int lx = threadIdx.x & 7, ly = threadIdx.x >> 3;
    int pxi = tX * 16 + (quad & 1) * 8 + lx;
    int pyi = tY * 16 + (quad >> 1) * 8 + ly;
    float px = pixc(pxi), py = pixc(pyi);
    int tile = tY * 16 + tX;

    const int* mylist = nullptr;
    int nf = NFACES;
    if (lists) {
        mylist = lists + ((size_t)b * 256 + tile) * NFACES;
        nf = counts[b * 256 + tile];
    }
    nf = __builtin_amdgcn_readfirstlane(nf);
    const float4* rb = rast + (size_t)b * NFACES * 3;

    float zmin = BIGF;
    float w0w = 0.0f, w1w = 0.0f;
    int fwin = -1;

    for (int base = 0; base < nf; base += CHUNKF) {
        int cnt = min(CHUNKF, nf - base);
        __syncthreads();
        for (int s = threadIdx.x; s < cnt; s += 64) {
            int fi = mylist ? mylist[base + s] : (base + s);
            const float4* p = rb + (size_t)fi * 3;
            sData[s*3+0] = p[0];
            sData[s*3+1] = p[1];
            sData[s*3+2] = p[2];
        }
        __syncthreads();
        for (int j = 0; j < cnt; ++j) {
            float4 r0 = sData[j*3+0];
            float4 r1 = sData[j*3+1];
            float4 r2 = sData[j*3+2];
            float dx = __fsub_rn(px, r0.x);
            float dy = __fsub_rn(py, r0.y);
            float w0 = __fmul_rn(__fadd_rn(__fmul_rn(r0.z, dx), __fmul_rn(r0.w, dy)), r1.z);
            float w1 = __fmul_rn(__fadd_rn(__fmul_rn(r1.x, dx), __fmul_rn(r1.y, dy)), r1.z);
            float w2 = __fsub_rn(__fsub_rn(1.0f, w0), w1);
            float d  = __fadd_rn(__fadd_rn(__fmul_rn(w0, r2.x), __fmul_rn(w1, r2.y)),
                                 __fmul_rn(w2, r2.z));
            bool ins = (w0 >= 0.0f) & (w1 >= 0.0f) & (w2 >= 0.0f) & (d < zmin);
            if (ins) { zmin = d; w0w = w0; w1w = w1; fwin = __float_as_int(r2.w); }
        }
    }

    // flow = w0*g0 + w1*g1 + w2*g2 (or -2 for background)
    float fx, fy;
    if (fwin >= 0) {
        const float4* fg = flowg + ((size_t)b * NFACES + fwin) * 2;
        float4 g0 = fg[0];
        float4 g1 = fg[1];
        float w2w = __fsub_rn(__fsub_rn(1.0f, w0w), w1w);
        fx = __fadd_rn(__fadd_rn(__fmul_rn(w0w, g0.x), __fmul_rn(w1w, g0.z)),
                       __fmul_rn(w2w, g1.x));
        fy = __fadd_rn(__fadd_rn(__fmul_rn(w0w, g0.y), __fmul_rn(w1w, g0.w)),
                       __fmul_rn(w2w, g1.y));
    } else {
        fx = -2.0f; fy = -2.0f;
    }

    // grid_sample, bilinear, border padding
    float ix = __fmul_rn(__fsub_rn(__fmul_rn(__fadd_rn(fx, 1.0f), 256.0f), 1.0f), 0.5f);
    float iy = __fmul_rn(__fsub_rn(__fmul_rn(__fadd_rn(fy, 1.0f), 256.0f), 1.0f), 0.5f);
    ix = fminf(fmaxf(ix, 0.0f), 255.0f);
    iy = fminf(fmaxf(iy, 0.0f), 255.0f);
    float x0f = floorf(ix), y0f = floorf(iy);
    float wx = __fsub_rn(ix, x0f), wy = __fsub_rn(iy, y0f);
    int x0i = (int)x0f, y0i = (int)y0f;
    int x1i = min(x0i + 1, 255), y1i = min(y0i + 1, 255);
    float omwx = __fsub_rn(1.0f, wx), omwy = __fsub_rn(1.0f, wy);
    float wa = __fmul_rn(omwx, omwy);
    float wb = __fmul_rn(wx, omwy);
    float wc = __fmul_rn(omwx, wy);
    float wd = __fmul_rn(wx, wy);
    const float* img = src_img + (size_t)b * 3 * HH * WW;
    int o00 = y0i * WW + x0i, o01 = y0i * WW + x1i;
    int o10 = y1i * WW + x0i, o11 = y1i * WW + x1i;
    float* ob = out + (size_t)b * 3 * HH * WW + (size_t)pyi * WW + pxi;
    for (int c = 0; c < 3; ++c) {
        const float* ic = img + (size_t)c * HH * WW;
        float Ia = ic[o00], Ib = ic[o01], Ic = ic[o10], Id = ic[o11];
        float val = __fadd_rn(__fadd_rn(__fadd_rn(__fmul_rn(Ia, wa), __fmul_rn(Ib, wb)),
                                        __fmul_rn(Ic, wc)),
                              __fmul_rn(Id, wd));
        ob[(size_t)c * HH * WW] = val;
    }
}

extern "C" void kernel_launch(void* const* d_in, const int* in_sizes, int n_in,
                              void* d_out, int out_size, void* d_ws, size_t ws_size,
                              hipStream_t stream)
{
    const float* src_img   = (const float*)d_in[0];
    const float* src_cam   = (const float*)d_in[1];
    const float* src_verts = (const float*)d_in[2];
    const float* tgt_cam   = (const float*)d_in[3];
    const float* tgt_verts = (const float*)d_in[4];
    const int*   faces     = (const int*)d_in[5];
    int B = in_sizes[1] / 3;   // src_cam is [B,3]

    size_t off = 0;
    auto alloc = [&](size_t bytes) {
        size_t o = off;
        off = (off + bytes + 255) & ~(size_t)255;
        return o;
    };
    size_t rastOff = alloc((size_t)B * NFACES * 3 * sizeof(float4));
    size_t flowOff = alloc((size_t)B * NFACES * 2 * sizeof(float4));
    size_t cntOff  = alloc((size_t)B * 256 * sizeof(int));
    size_t listOff = alloc((size_t)B * 256 * NFACES * sizeof(int));
    bool binned = (off <= ws_size);

    char* ws = (char*)d_ws;
    float4* rast  = (float4*)(ws + rastOff);
    float4* flowg = (float4*)(ws + flowOff);
    int* counts = binned ? (int*)(ws + cntOff)  : nullptr;
    int* lists  = binned ? (int*)(ws + listOff) : nullptr;

    int total = B * NFACES;
    precompute_kernel<<<(total + 255) / 256, 256, 0, stream>>>(
        src_cam, src_verts, tgt_cam, tgt_verts, faces, rast, flowg, B);
    if (binned) {
        bin_kernel<<<dim3(256, B), 256, 0, stream>>>(rast, lists, counts, B);
    }
    raster_kernel<<<dim3(16, 16, B * 4), 64, 0, stream>>>(
        rast, flowg, lists, counts, src_img, (float*)d_out, B);
}